// Round 7
// baseline (356.805 us; speedup 1.0000x reference)
//
#include <hip/hip_runtime.h>
#include <hip/hip_bf16.h>
#include <math.h>

#define BATCH 4096
#define IDIM 78
#define DM 256
#define DI 1024
#define NL 4

typedef __attribute__((ext_vector_type(8))) short bf16x8;
typedef __attribute__((ext_vector_type(4))) float f32x4;

__device__ __forceinline__ float siluf(float v){ return v / (1.0f + __expf(-v)); }
__device__ __forceinline__ float softplusf(float v){ return (v > 20.0f) ? v : log1pf(__expf(v)); }
__device__ __forceinline__ ushort f2bf(float f){
  union { float f; unsigned u; } c; c.f = f;
  unsigned r = c.u + 0x7fff + ((c.u >> 16) & 1);
  return (ushort)(r >> 16);
}
__device__ __forceinline__ float bf2f(ushort b){
  union { unsigned u; float f; } c; c.u = ((unsigned)b) << 16; return c.f;
}

// ---------- fused weight prep: WinT, WoutT (32x32 transpose tiles) + WxT ----------
__device__ __forceinline__ void tconv_tile(const float* __restrict__ src, ushort* __restrict__ dst,
    int R, int C, int r0, int c0, float (*tile)[33]){
  int t = threadIdx.x, ci = t & 31, rq = t >> 5;
  #pragma unroll
  for (int p=0;p<4;p++){ int ri = p*8 + rq; tile[ri][ci] = src[(size_t)(r0+ri)*C + c0 + ci]; }
  __syncthreads();
  #pragma unroll
  for (int p=0;p<4;p++){ int ri = p*8 + rq; dst[(size_t)(c0+ri)*R + r0 + ci] = f2bf(tile[ci][ri]); }
}

__global__ __launch_bounds__(256) void k_prep(const float* __restrict__ Win,
    const float* __restrict__ Wout, const float* __restrict__ Wx,
    ushort* __restrict__ WinT, ushort* __restrict__ WoutT, ushort* __restrict__ WxT){
  __shared__ float tile[32][33];
  int bid = blockIdx.x;
  if (bid < 2048){                       // Win [l][256][2048] -> WinT [l][2048][256]
    int x = bid & 63, y = (bid >> 6) & 7, l = bid >> 9;
    tconv_tile(Win + (size_t)l*DM*2*DI, WinT + (size_t)l*2*DI*DM, DM, 2*DI, y*32, x*32, tile);
  } else if (bid < 3072){                // Wout [l][1024][256] -> WoutT [l][256][1024]
    int b = bid - 2048;
    int x = b & 7, y = (b >> 3) & 31, l = b >> 8;
    tconv_tile(Wout + (size_t)l*DI*DM, WoutT + (size_t)l*DM*DI, DI, DM, y*32, x*32, tile);
  } else {                               // Wx [l][1024][80] -> WxT [l][80][1024]
    int b = bid - 3072;
    int x = b & 3, y = (b >> 2) % 80, l = b / 320;
    int k = x*256 + threadIdx.x;
    WxT[(size_t)l*80*DI + (size_t)y*DI + k] = f2bf(Wx[(size_t)l*DI*80 + (size_t)k*80 + y]);
  }
}

// ---------- proj_in + rmsnorm(layer0): 16 rows/block, coalesced Wp ----------
__global__ __launch_bounds__(256) void k_proj_in(const float* __restrict__ x,
    const float* __restrict__ Wp, const float* __restrict__ bp,
    const float* __restrict__ nw, float* __restrict__ h, ushort* __restrict__ xn){
  __shared__ float xs[16][80];
  __shared__ float sred[16][4];
  __shared__ float ssc[16];
  int row0 = blockIdx.x*16;
  int t = threadIdx.x, wid = t>>6;
  if (t < IDIM){
    #pragma unroll
    for (int r=0;r<16;r++) xs[r][t] = x[(size_t)(row0+r)*IDIM + t];
  }
  __syncthreads();
  int col = t;
  float acc[16];
  float b0 = bp[col];
  #pragma unroll
  for (int r=0;r<16;r++) acc[r] = b0;
  for (int k=0;k<IDIM;k++){
    float wv = Wp[k*DM + col];
    #pragma unroll
    for (int r=0;r<16;r++) acc[r] = fmaf(xs[r][k], wv, acc[r]);
  }
  #pragma unroll
  for (int r=0;r<16;r++){
    float sq = acc[r]*acc[r];
    #pragma unroll
    for (int o=32;o>0;o>>=1) sq += __shfl_xor(sq, o);
    if ((t&63)==0) sred[r][wid] = sq;
  }
  __syncthreads();
  if (t < 16){
    float tot = sred[t][0]+sred[t][1]+sred[t][2]+sred[t][3];
    ssc[t] = rsqrtf(tot*(1.0f/DM) + 1e-5f);
  }
  __syncthreads();
  float nwv = nw[col];
  #pragma unroll
  for (int r=0;r<16;r++){
    size_t o = (size_t)(row0+r)*DM + col;
    h[o] = acc[r];
    xn[o] = f2bf(acc[r]*ssc[r]*nwv);
  }
}

// ---------- k_blk0: barrier-free direct-register MFMA GEMM, 128x128, K=256 ----------
// xn @ WinT^T ; conv/silu epilogue -> xi / sz via LDS-staged coalesced stores
__global__ __launch_bounds__(256) void k_blk0(
    const ushort* __restrict__ A,     // xn [4096][256]
    const ushort* __restrict__ Bt,    // WinT [2048][256]
    const float* __restrict__ cwl, const float* __restrict__ cbl,
    ushort* __restrict__ xi, ushort* __restrict__ sz)
{
  __shared__ ushort cs[128][136];     // 34.8 KB epilogue tile (pad 8)
  int t = threadIdx.x;
  int row0 = blockIdx.x*128, col0 = blockIdx.y*128;
  int wid = t>>6, lane = t&63;
  int wr = wid>>1, wc = wid&1, lr = lane&15, lk = lane>>4;
  const ushort* Aw = A  + (size_t)(row0 + wr*64 + lr)*DM + lk*8;
  const ushort* Bw = Bt + (size_t)(col0 + wc*64 + lr)*DM + lk*8;
  f32x4 acc[4][4] = {};
  #pragma unroll
  for (int kc=0; kc<DM/32; ++kc){
    bf16x8 av[4], bv[4];
    #pragma unroll
    for (int i=0;i<4;i++) av[i] = *(const bf16x8*)(Aw + (size_t)i*16*DM + kc*32);
    #pragma unroll
    for (int j=0;j<4;j++) bv[j] = *(const bf16x8*)(Bw + (size_t)j*16*DM + kc*32);
    #pragma unroll
    for (int i=0;i<4;i++)
      #pragma unroll
      for (int j=0;j<4;j++)
        acc[i][j] = __builtin_amdgcn_mfma_f32_16x16x32_bf16(av[i], bv[j], acc[i][j], 0,0,0);
  }
  const bool is_xi = (col0 < DI);
  float scw[4], scb[4];
  if (is_xi){
    #pragma unroll
    for (int j=0;j<4;j++){
      int colb = col0 + wc*64 + j*16 + lr;
      scw[j] = cwl[colb*16+15];
      scb[j] = cbl[colb];
    }
  }
  #pragma unroll
  for (int i=0;i<4;i++)
    #pragma unroll
    for (int j=0;j<4;j++){
      int cl = wc*64 + j*16 + lr;
      #pragma unroll
      for (int r=0;r<4;r++){
        int rl = wr*64 + i*16 + lk*4 + r;
        float v = acc[i][j][r];
        float o = is_xi ? siluf(fmaf(scw[j], v, scb[j])) : siluf(v);
        cs[rl][cl] = f2bf(o);
      }
    }
  __syncthreads();
  ushort* dst = is_xi ? (xi + col0) : (sz + col0 - DI);
  int rsub = t>>4, c8 = (t&15)*8;
  #pragma unroll
  for (int p=0;p<8;p++){
    int rl = p*16 + rsub;
    *(uint4*)&dst[(size_t)(row0+rl)*DI + c8] = *(uint4*)&cs[rl][c8];
  }
}

// ---------- k_ssm: fused dbc (MFMA split-K in block) + delta + gating; in-place y over xi ----------
__global__ __launch_bounds__(512) void k_ssm(const ushort* __restrict__ xi, const ushort* __restrict__ sz,
    const ushort* __restrict__ WxT, const float* __restrict__ Wdt, const float* __restrict__ bdt,
    const float* __restrict__ Dd, ushort* __restrict__ y){
  __shared__ float dsum[8][16][81];
  __shared__ float sS[16];
  int r0 = blockIdx.x*16;
  int t = threadIdx.x, w = t>>6, lane = t&63, lr = lane&15, lk = lane>>4;
  f32x4 acc[5] = {};
  const ushort* Ab = xi  + (size_t)(r0+lr)*DI + w*128 + lk*8;
  const ushort* Bb = WxT + (size_t)lr*DI      + w*128 + lk*8;
  #pragma unroll
  for (int s=0;s<4;s++){
    bf16x8 a = *(const bf16x8*)(Ab + s*32);
    #pragma unroll
    for (int j=0;j<5;j++){
      bf16x8 b = *(const bf16x8*)(Bb + (size_t)j*16*DI + s*32);
      acc[j] = __builtin_amdgcn_mfma_f32_16x16x32_bf16(a, b, acc[j], 0,0,0);
    }
  }
  #pragma unroll
  for (int j=0;j<5;j++)
    #pragma unroll
    for (int r=0;r<4;r++)
      dsum[w][lk*4+r][j*16+lr] = acc[j][r];
  __syncthreads();
  for (int idx=t; idx<16*80; idx+=512){
    int rr = idx/80, n = idx%80;
    float s = dsum[0][rr][n];
    #pragma unroll
    for (int q=1;q<8;q++) s += dsum[q][rr][n];
    dsum[0][rr][n] = s;
  }
  __syncthreads();
  if (t < 256){
    int row = t>>4, ln = t&15;
    float p = dsum[0][row][16+ln]*dsum[0][row][48+ln]
            + dsum[0][row][32+ln]*dsum[0][row][64+ln];
    p += __shfl_xor(p, 8); p += __shfl_xor(p, 4); p += __shfl_xor(p, 2); p += __shfl_xor(p, 1);
    if (ln==0) sS[row] = p;
  }
  __syncthreads();
  int e = 2*t;
  float2 wdtr[16];
  #pragma unroll
  for (int r=0;r<16;r++) wdtr[r] = *(const float2*)(Wdt + (size_t)r*DI + e);
  float2 bd = *(const float2*)(bdt + e);
  float2 dd = *(const float2*)(Dd + e);
  for (int row=0; row<16; ++row){
    float u0 = bd.x, u1 = bd.y;
    #pragma unroll
    for (int r=0;r<16;r++){ float dv = dsum[0][row][r]; u0 = fmaf(wdtr[r].x, dv, u0); u1 = fmaf(wdtr[r].y, dv, u1); }
    float srow = sS[row];
    float d0 = softplusf(u0), d1 = softplusf(u1);
    size_t o = (size_t)(r0+row)*DI + e;
    ushort2 xv = *(const ushort2*)(xi + o);
    ushort2 zv = *(const ushort2*)(sz + o);
    ushort2 ov;
    ov.x = f2bf(bf2f(xv.x) * fmaf(d0, srow, dd.x) * bf2f(zv.x));
    ov.y = f2bf(bf2f(xv.y) * fmaf(d1, srow, dd.y) * bf2f(zv.y));
    *(ushort2*)(y + o) = ov;
  }
}

// ---------- k_blk1: y @ WoutT^T -> h += (coalesced fp32 RMW via LDS tile). 32x64, K=1024 ----------
__global__ __launch_bounds__(256) void k_blk1(
    const ushort* __restrict__ A,    // y [4096][1024]
    const ushort* __restrict__ Bt,   // WoutT [256][1024]
    float* __restrict__ h)
{
  __shared__ float ls[32][68];       // 8.7 KB epilogue tile
  int t = threadIdx.x, wid = t>>6, lane = t&63;
  int wr = wid>>1, wc = wid&1, lr = lane&15, lk = lane>>4;
  int row0 = blockIdx.x*32, col0 = blockIdx.y*64;
  const ushort* Aw = A  + (size_t)(row0 + wr*16 + lr)*DI + lk*8;
  const ushort* Bw = Bt + (size_t)(col0 + wc*32 + lr)*DI + lk*8;
  f32x4 acc[2] = {};
  #pragma unroll
  for (int kc=0; kc<DI/32; ++kc){
    bf16x8 a  = *(const bf16x8*)(Aw + kc*32);
    bf16x8 b0 = *(const bf16x8*)(Bw + kc*32);
    bf16x8 b1 = *(const bf16x8*)(Bw + (size_t)16*DI + kc*32);
    acc[0] = __builtin_amdgcn_mfma_f32_16x16x32_bf16(a, b0, acc[0], 0,0,0);
    acc[1] = __builtin_amdgcn_mfma_f32_16x16x32_bf16(a, b1, acc[1], 0,0,0);
  }
  #pragma unroll
  for (int j=0;j<2;j++){
    int cl = wc*32 + j*16 + lr;
    #pragma unroll
    for (int r=0;r<4;r++)
      ls[wr*16 + lk*4 + r][cl] = acc[j][r];
  }
  __syncthreads();
  int rsub = t>>4, c4 = (t&15)*4;
  #pragma unroll
  for (int p=0;p<2;p++){
    int rl = p*16 + rsub;
    float4 add = *(float4*)&ls[rl][c4];
    size_t o = (size_t)(row0+rl)*DM + col0 + c4;
    float4 hv = *(float4*)&h[o];
    hv.x += add.x; hv.y += add.y; hv.z += add.z; hv.w += add.w;
    *(float4*)&h[o] = hv;
  }
}

// ---------- k_norm: rmsnorm h -> xn (bf16); LAST: final dot + sigmoid -> out ----------
template<int LAST>
__global__ __launch_bounds__(256) void k_norm(const float* __restrict__ h,
    const float* __restrict__ nw, const float* __restrict__ Wf,
    const float* __restrict__ bf, ushort* __restrict__ xn, float* __restrict__ out){
  __shared__ float sred[16][4];
  __shared__ float sfin[16][4];
  __shared__ float ssc[16];
  int row0 = blockIdx.x*16;
  int t = threadIdx.x, wid = t>>6;
  float v[16];
  #pragma unroll
  for (int r=0;r<16;r++) v[r] = h[(size_t)(row0+r)*DM + t];
  float wf = 0.f;
  if constexpr (LAST) wf = Wf[t];
  #pragma unroll
  for (int r=0;r<16;r++){
    float sq = v[r]*v[r];
    float pf = LAST ? v[r]*wf : 0.f;
    #pragma unroll
    for (int o=32;o>0;o>>=1){
      sq += __shfl_xor(sq, o);
      if constexpr (LAST) pf += __shfl_xor(pf, o);
    }
    if ((t&63)==0){ sred[r][wid] = sq; if constexpr (LAST) sfin[r][wid] = pf; }
  }
  __syncthreads();
  if (t < 16){
    float tot = sred[t][0]+sred[t][1]+sred[t][2]+sred[t][3];
    ssc[t] = rsqrtf(tot*(1.0f/DM) + 1e-5f);
    if constexpr (LAST){
      float ft = sfin[t][0]+sfin[t][1]+sfin[t][2]+sfin[t][3];
      out[row0 + t] = 1.0f/(1.0f + __expf(-(ft + bf[0])));
    }
  }
  __syncthreads();
  if constexpr (!LAST){
    float nwv = nw[t];
    #pragma unroll
    for (int r=0;r<16;r++)
      xn[(size_t)(row0+r)*DM + t] = f2bf(v[r]*ssc[r]*nwv);
  }
}

extern "C" void kernel_launch(void* const* d_in, const int* in_sizes, int n_in,
                              void* d_out, int out_size, void* d_ws, size_t ws_size,
                              hipStream_t stream){
  const float* x   = (const float*)d_in[0];
  const float* Wp  = (const float*)d_in[1];
  const float* bp  = (const float*)d_in[2];
  const float* nw  = (const float*)d_in[3];
  const float* Win = (const float*)d_in[4];
  const float* cw  = (const float*)d_in[5];
  const float* cb  = (const float*)d_in[6];
  const float* Wx  = (const float*)d_in[7];
  const float* Wdt = (const float*)d_in[8];
  const float* bdt = (const float*)d_in[9];
  const float* Dd  = (const float*)d_in[11];   // A_log (d_in[10]) is dead: scan length 1, h0 = 0
  const float* Wout= (const float*)d_in[12];
  const float* Wf  = (const float*)d_in[13];
  const float* bf  = (const float*)d_in[14];
  float* out = (float*)d_out;

  char* wsb = (char*)d_ws;
  float*  h    = (float*)wsb;  wsb += (size_t)BATCH*DM*4;          // 4 MB
  ushort* xn   = (ushort*)wsb; wsb += (size_t)BATCH*DM*2;          // 2 MB
  ushort* xi   = (ushort*)wsb; wsb += (size_t)BATCH*DI*2;          // 8 MB
  ushort* sz   = (ushort*)wsb; wsb += (size_t)BATCH*DI*2;          // 8 MB
  ushort* WinT = (ushort*)wsb; wsb += (size_t)NL*2*DI*DM*2;        // 4 MB
  ushort* WoutT= (ushort*)wsb; wsb += (size_t)NL*DM*DI*2;          // 2 MB
  ushort* WxT  = (ushort*)wsb; wsb += (size_t)NL*80*DI*2;          // 0.64 MB

  k_prep<<<4352, 256, 0, stream>>>(Win, Wout, Wx, WinT, WoutT, WxT);
  k_proj_in<<<BATCH/16, 256, 0, stream>>>(x, Wp, bp, nw, h, xn);
  for (int l=0;l<NL;l++){
    k_blk0<<<dim3(BATCH/128, (2*DI)/128), 256, 0, stream>>>(
        xn, WinT + (size_t)l*2*DI*DM,
        cw + (size_t)l*DI*16, cb + (size_t)l*DI, xi, sz);
    k_ssm<<<BATCH/16, 512, 0, stream>>>(xi, sz, WxT + (size_t)l*80*DI,
        Wdt + (size_t)l*16*DI, bdt + (size_t)l*DI, Dd + (size_t)l*DI, xi);
    k_blk1<<<dim3(BATCH/32, DM/64), 256, 0, stream>>>(
        xi, WoutT + (size_t)l*DM*DI, h);
    if (l < NL-1)
      k_norm<0><<<BATCH/16, 256, 0, stream>>>(h, nw + (l+1)*DM, nullptr, nullptr, xn, nullptr);
    else
      k_norm<1><<<BATCH/16, 256, 0, stream>>>(h, nullptr, Wf, bf, nullptr, out);
  }
}

// Round 8
// 262.408 us; speedup vs baseline: 1.3597x; 1.3597x over previous
//
#include <hip/hip_runtime.h>
#include <hip/hip_bf16.h>
#include <math.h>

#define BATCH 4096
#define IDIM 78
#define DM 256
#define DI 1024
#define NL 4

typedef __attribute__((ext_vector_type(8))) short bf16x8;
typedef __attribute__((ext_vector_type(4))) float f32x4;

__device__ __forceinline__ float siluf(float v){ return v / (1.0f + __expf(-v)); }
__device__ __forceinline__ float softplusf(float v){ return (v > 20.0f) ? v : log1pf(__expf(v)); }
__device__ __forceinline__ ushort f2bf(float f){
  union { float f; unsigned u; } c; c.f = f;
  unsigned r = c.u + 0x7fff + ((c.u >> 16) & 1);
  return (ushort)(r >> 16);
}
__device__ __forceinline__ float bf2f(ushort b){
  union { unsigned u; float f; } c; c.u = ((unsigned)b) << 16; return c.f;
}
// async global->LDS, 16B/lane; LDS dest = wave-uniform base + lane*16; global src per-lane
__device__ __forceinline__ void async_copy16(void* lds, const void* g){
  __builtin_amdgcn_global_load_lds(
      (const __attribute__((address_space(1))) unsigned int*)g,
      (__attribute__((address_space(3))) unsigned int*)lds, 16, 0, 0);
}

// ---------- fused weight prep: WinT, WoutT (32x32 transpose tiles) + WxT ----------
__device__ __forceinline__ void tconv_tile(const float* __restrict__ src, ushort* __restrict__ dst,
    int R, int C, int r0, int c0, float (*tile)[33]){
  int t = threadIdx.x, ci = t & 31, rq = t >> 5;
  #pragma unroll
  for (int p=0;p<4;p++){ int ri = p*8 + rq; tile[ri][ci] = src[(size_t)(r0+ri)*C + c0 + ci]; }
  __syncthreads();
  #pragma unroll
  for (int p=0;p<4;p++){ int ri = p*8 + rq; dst[(size_t)(c0+ri)*R + r0 + ci] = f2bf(tile[ci][ri]); }
}

__global__ __launch_bounds__(256) void k_prep(const float* __restrict__ Win,
    const float* __restrict__ Wout, const float* __restrict__ Wx,
    ushort* __restrict__ WinT, ushort* __restrict__ WoutT, ushort* __restrict__ WxT){
  __shared__ float tile[32][33];
  int bid = blockIdx.x;
  if (bid < 2048){                       // Win [l][256][2048] -> WinT [l][2048][256]
    int x = bid & 63, y = (bid >> 6) & 7, l = bid >> 9;
    tconv_tile(Win + (size_t)l*DM*2*DI, WinT + (size_t)l*2*DI*DM, DM, 2*DI, y*32, x*32, tile);
  } else if (bid < 3072){                // Wout [l][1024][256] -> WoutT [l][256][1024]
    int b = bid - 2048;
    int x = b & 7, y = (b >> 3) & 31, l = b >> 8;
    tconv_tile(Wout + (size_t)l*DI*DM, WoutT + (size_t)l*DM*DI, DI, DM, y*32, x*32, tile);
  } else {                               // Wx [l][1024][80] -> WxT [l][80][1024]
    int b = bid - 3072;
    int x = b & 3, y = (b >> 2) % 80, l = b / 320;
    int k = x*256 + threadIdx.x;
    WxT[(size_t)l*80*DI + (size_t)y*DI + k] = f2bf(Wx[(size_t)l*DI*80 + (size_t)k*80 + y]);
  }
}

// ---------- proj_in + rmsnorm(layer0): 16 rows/block, coalesced Wp ----------
__global__ __launch_bounds__(256) void k_proj_in(const float* __restrict__ x,
    const float* __restrict__ Wp, const float* __restrict__ bp,
    const float* __restrict__ nw, float* __restrict__ h, ushort* __restrict__ xn){
  __shared__ float xs[16][80];
  __shared__ float sred[16][4];
  __shared__ float ssc[16];
  int row0 = blockIdx.x*16;
  int t = threadIdx.x, wid = t>>6;
  if (t < IDIM){
    #pragma unroll
    for (int r=0;r<16;r++) xs[r][t] = x[(size_t)(row0+r)*IDIM + t];
  }
  __syncthreads();
  int col = t;
  float acc[16];
  float b0 = bp[col];
  #pragma unroll
  for (int r=0;r<16;r++) acc[r] = b0;
  for (int k=0;k<IDIM;k++){
    float wv = Wp[k*DM + col];
    #pragma unroll
    for (int r=0;r<16;r++) acc[r] = fmaf(xs[r][k], wv, acc[r]);
  }
  #pragma unroll
  for (int r=0;r<16;r++){
    float sq = acc[r]*acc[r];
    #pragma unroll
    for (int o=32;o>0;o>>=1) sq += __shfl_xor(sq, o);
    if ((t&63)==0) sred[r][wid] = sq;
  }
  __syncthreads();
  if (t < 16){
    float tot = sred[t][0]+sred[t][1]+sred[t][2]+sred[t][3];
    ssc[t] = rsqrtf(tot*(1.0f/DM) + 1e-5f);
  }
  __syncthreads();
  float nwv = nw[col];
  #pragma unroll
  for (int r=0;r<16;r++){
    size_t o = (size_t)(row0+r)*DM + col;
    h[o] = acc[r];
    xn[o] = f2bf(acc[r]*ssc[r]*nwv);
  }
}

// ---------- k_blk0: 64x64 tile, ONE-SHOT K=256 staging (1 barrier), XOR-8 swizzle ----------
// xn @ WinT^T ; conv/silu epilogue -> xi / sz via LDS-staged coalesced stores
__global__ __launch_bounds__(256) void k_blk0(
    const ushort* __restrict__ A,     // xn [4096][256]
    const ushort* __restrict__ Bt,    // WinT [2048][256]
    const float* __restrict__ cwl, const float* __restrict__ cbl,
    ushort* __restrict__ xi, ushort* __restrict__ sz)
{
  __shared__ __align__(16) ushort As[64][256];   // 32 KB
  __shared__ __align__(16) ushort Bs[64][256];   // 32 KB
  int t = threadIdx.x;
  int row0 = blockIdx.x*64, col0 = blockIdx.y*64;
  int wid = t>>6, lane = t&63;
  int wr = wid>>1, wc = wid&1, lr = lane&15, lk = lane>>4;
  int lrow = lane>>5, lch = lane&31;     // staging: 2 rows x 32 chunks per inst

  // one-shot stage: per wave 8 A-insts + 8 B-insts, rows wid*16..+15
  #pragma unroll
  for (int q=0;q<8;q++){
    int rr = wid*16 + q*2 + lrow;
    async_copy16(&As[wid*16 + q*2][0], A  + (size_t)(row0+rr)*DM + ((lch ^ (rr&7))<<3));
  }
  #pragma unroll
  for (int q=0;q<8;q++){
    int rr = wid*16 + q*2 + lrow;
    async_copy16(&Bs[wid*16 + q*2][0], Bt + (size_t)(col0+rr)*DM + ((lch ^ (rr&7))<<3));
  }
  __syncthreads();

  f32x4 acc[2][2] = {};
  #pragma unroll
  for (int kk=0;kk<8;kk++){
    bf16x8 av[2], bv[2];
    #pragma unroll
    for (int i=0;i<2;i++){ int rr = wr*32 + i*16 + lr; av[i] = *(const bf16x8*)&As[rr][(((kk<<2)|lk) ^ (rr&7))<<3]; }
    #pragma unroll
    for (int j=0;j<2;j++){ int cc = wc*32 + j*16 + lr; bv[j] = *(const bf16x8*)&Bs[cc][(((kk<<2)|lk) ^ (cc&7))<<3]; }
    #pragma unroll
    for (int i=0;i<2;i++)
      #pragma unroll
      for (int j=0;j<2;j++)
        acc[i][j] = __builtin_amdgcn_mfma_f32_16x16x32_bf16(av[i], bv[j], acc[i][j], 0,0,0);
  }

  const bool is_xi = (col0 < DI);
  float scw[2], scb[2];
  if (is_xi){
    #pragma unroll
    for (int j=0;j<2;j++){
      int colb = col0 + wc*32 + j*16 + lr;
      scw[j] = cwl[colb*16+15];
      scb[j] = cbl[colb];
    }
  }
  __syncthreads();                         // all MFMA reads done; reuse As as epilogue tile
  ushort* cs = &As[0][0];                  // [64][72]
  #pragma unroll
  for (int i=0;i<2;i++)
    #pragma unroll
    for (int j=0;j<2;j++){
      int cl = wc*32 + j*16 + lr;
      #pragma unroll
      for (int r=0;r<4;r++){
        int rl = wr*32 + i*16 + lk*4 + r;
        float v = acc[i][j][r];
        cs[rl*72 + cl] = f2bf(is_xi ? siluf(fmaf(scw[j], v, scb[j])) : siluf(v));
      }
    }
  __syncthreads();
  int rl = t>>2, c16 = (t&3)*16;
  ushort* drow = (is_xi ? (xi + col0) : (sz + col0 - DI)) + (size_t)(row0+rl)*DI + c16;
  *(uint4*)&drow[0] = *(uint4*)&cs[rl*72 + c16];
  *(uint4*)&drow[8] = *(uint4*)&cs[rl*72 + c16 + 8];
}

// ---------- k_ssm: fused dbc (MFMA split-K in block) + delta + gating; in-place y over xi ----------
__global__ __launch_bounds__(512) void k_ssm(const ushort* __restrict__ xi, const ushort* __restrict__ sz,
    const ushort* __restrict__ WxT, const float* __restrict__ Wdt, const float* __restrict__ bdt,
    const float* __restrict__ Dd, ushort* __restrict__ y){
  __shared__ float dsum[8][16][81];
  __shared__ float sS[16];
  int r0 = blockIdx.x*16;
  int t = threadIdx.x, w = t>>6, lane = t&63, lr = lane&15, lk = lane>>4;
  f32x4 acc[5] = {};
  const ushort* Ab = xi  + (size_t)(r0+lr)*DI + w*128 + lk*8;
  const ushort* Bb = WxT + (size_t)lr*DI      + w*128 + lk*8;
  #pragma unroll
  for (int s=0;s<4;s++){
    bf16x8 a = *(const bf16x8*)(Ab + s*32);
    #pragma unroll
    for (int j=0;j<5;j++){
      bf16x8 b = *(const bf16x8*)(Bb + (size_t)j*16*DI + s*32);
      acc[j] = __builtin_amdgcn_mfma_f32_16x16x32_bf16(a, b, acc[j], 0,0,0);
    }
  }
  #pragma unroll
  for (int j=0;j<5;j++)
    #pragma unroll
    for (int r=0;r<4;r++)
      dsum[w][lk*4+r][j*16+lr] = acc[j][r];
  __syncthreads();
  for (int idx=t; idx<16*80; idx+=512){
    int rr = idx/80, n = idx%80;
    float s = dsum[0][rr][n];
    #pragma unroll
    for (int q=1;q<8;q++) s += dsum[q][rr][n];
    dsum[0][rr][n] = s;
  }
  __syncthreads();
  if (t < 256){
    int row = t>>4, ln = t&15;
    float p = dsum[0][row][16+ln]*dsum[0][row][48+ln]
            + dsum[0][row][32+ln]*dsum[0][row][64+ln];
    p += __shfl_xor(p, 8); p += __shfl_xor(p, 4); p += __shfl_xor(p, 2); p += __shfl_xor(p, 1);
    if (ln==0) sS[row] = p;
  }
  __syncthreads();
  int e = 2*t;
  float2 wdtr[16];
  #pragma unroll
  for (int r=0;r<16;r++) wdtr[r] = *(const float2*)(Wdt + (size_t)r*DI + e);
  float2 bd = *(const float2*)(bdt + e);
  float2 dd = *(const float2*)(Dd + e);
  for (int row=0; row<16; ++row){
    float u0 = bd.x, u1 = bd.y;
    #pragma unroll
    for (int r=0;r<16;r++){ float dv = dsum[0][row][r]; u0 = fmaf(wdtr[r].x, dv, u0); u1 = fmaf(wdtr[r].y, dv, u1); }
    float srow = sS[row];
    float d0 = softplusf(u0), d1 = softplusf(u1);
    size_t o = (size_t)(r0+row)*DI + e;
    ushort2 xv = *(const ushort2*)(xi + o);
    ushort2 zv = *(const ushort2*)(sz + o);
    ushort2 ov;
    ov.x = f2bf(bf2f(xv.x) * fmaf(d0, srow, dd.x) * bf2f(zv.x));
    ov.y = f2bf(bf2f(xv.y) * fmaf(d1, srow, dd.y) * bf2f(zv.y));
    *(ushort2*)(y + o) = ov;
  }
}

// ---------- k_blk1: 32x64 tile, BK=256 staged (4 one-shot chunks), y @ WoutT^T -> h += ----------
__global__ __launch_bounds__(256) void k_blk1(
    const ushort* __restrict__ A,    // y [4096][1024]
    const ushort* __restrict__ Bt,   // WoutT [256][1024]
    float* __restrict__ h)
{
  __shared__ __align__(16) ushort As[32][256];  // 16 KB
  __shared__ __align__(16) ushort Bs[64][256];  // 32 KB
  int t = threadIdx.x, wid = t>>6, lane = t&63;
  int wr = wid>>1, wc = wid&1, lr = lane&15, lk = lane>>4;
  int row0 = blockIdx.x*32, col0 = blockIdx.y*64;
  int lrow = lane>>5, lch = lane&31;
  f32x4 acc[2] = {};

  for (int kc=0; kc<4; ++kc){
    int ko = kc*256;
    #pragma unroll
    for (int q=0;q<4;q++){
      int rr = wid*8 + q*2 + lrow;
      async_copy16(&As[wid*8 + q*2][0], A  + (size_t)(row0+rr)*DI + ko + ((lch ^ (rr&7))<<3));
    }
    #pragma unroll
    for (int q=0;q<8;q++){
      int rr = wid*16 + q*2 + lrow;
      async_copy16(&Bs[wid*16 + q*2][0], Bt + (size_t)(col0+rr)*DI + ko + ((lch ^ (rr&7))<<3));
    }
    __syncthreads();
    #pragma unroll
    for (int kk=0;kk<8;kk++){
      int rr = wr*16 + lr;
      bf16x8 a = *(const bf16x8*)&As[rr][(((kk<<2)|lk) ^ (rr&7))<<3];
      #pragma unroll
      for (int j=0;j<2;j++){
        int cc = wc*32 + j*16 + lr;
        bf16x8 b = *(const bf16x8*)&Bs[cc][(((kk<<2)|lk) ^ (cc&7))<<3];
        acc[j] = __builtin_amdgcn_mfma_f32_16x16x32_bf16(a, b, acc[j], 0,0,0);
      }
    }
    __syncthreads();
  }

  // epilogue: fp32 tile in LDS (reuse As region) -> coalesced float4 RMW of h
  float* ls = (float*)&As[0][0];          // [32][68]
  #pragma unroll
  for (int j=0;j<2;j++){
    int cl = wc*32 + j*16 + lr;
    #pragma unroll
    for (int r=0;r<4;r++)
      ls[(wr*16 + lk*4 + r)*68 + cl] = acc[j][r];
  }
  __syncthreads();
  int rl = t>>3, c8 = (t&7)*8;
  size_t o = (size_t)(row0+rl)*DM + col0 + c8;
  #pragma unroll
  for (int p=0;p<2;p++){
    float4 add = *(float4*)&ls[rl*68 + c8 + p*4];
    float4 hv = *(float4*)&h[o + p*4];
    hv.x += add.x; hv.y += add.y; hv.z += add.z; hv.w += add.w;
    *(float4*)&h[o + p*4] = hv;
  }
}

// ---------- k_norm: rmsnorm h -> xn (bf16); LAST: final dot + sigmoid -> out ----------
template<int LAST>
__global__ __launch_bounds__(256) void k_norm(const float* __restrict__ h,
    const float* __restrict__ nw, const float* __restrict__ Wf,
    const float* __restrict__ bf, ushort* __restrict__ xn, float* __restrict__ out){
  __shared__ float sred[16][4];
  __shared__ float sfin[16][4];
  __shared__ float ssc[16];
  int row0 = blockIdx.x*16;
  int t = threadIdx.x, wid = t>>6;
  float v[16];
  #pragma unroll
  for (int r=0;r<16;r++) v[r] = h[(size_t)(row0+r)*DM + t];
  float wf = 0.f;
  if constexpr (LAST) wf = Wf[t];
  #pragma unroll
  for (int r=0;r<16;r++){
    float sq = v[r]*v[r];
    float pf = LAST ? v[r]*wf : 0.f;
    #pragma unroll
    for (int o=32;o>0;o>>=1){
      sq += __shfl_xor(sq, o);
      if constexpr (LAST) pf += __shfl_xor(pf, o);
    }
    if ((t&63)==0){ sred[r][wid] = sq; if constexpr (LAST) sfin[r][wid] = pf; }
  }
  __syncthreads();
  if (t < 16){
    float tot = sred[t][0]+sred[t][1]+sred[t][2]+sred[t][3];
    ssc[t] = rsqrtf(tot*(1.0f/DM) + 1e-5f);
    if constexpr (LAST){
      float ft = sfin[t][0]+sfin[t][1]+sfin[t][2]+sfin[t][3];
      out[row0 + t] = 1.0f/(1.0f + __expf(-(ft + bf[0])));
    }
  }
  __syncthreads();
  if constexpr (!LAST){
    float nwv = nw[t];
    #pragma unroll
    for (int r=0;r<16;r++)
      xn[(size_t)(row0+r)*DM + t] = f2bf(v[r]*ssc[r]*nwv);
  }
}

extern "C" void kernel_launch(void* const* d_in, const int* in_sizes, int n_in,
                              void* d_out, int out_size, void* d_ws, size_t ws_size,
                              hipStream_t stream){
  const float* x   = (const float*)d_in[0];
  const float* Wp  = (const float*)d_in[1];
  const float* bp  = (const float*)d_in[2];
  const float* nw  = (const float*)d_in[3];
  const float* Win = (const float*)d_in[4];
  const float* cw  = (const float*)d_in[5];
  const float* cb  = (const float*)d_in[6];
  const float* Wx  = (const float*)d_in[7];
  const float* Wdt = (const float*)d_in[8];
  const float* bdt = (const float*)d_in[9];
  const float* Dd  = (const float*)d_in[11];   // A_log (d_in[10]) is dead: scan length 1, h0 = 0
  const float* Wout= (const float*)d_in[12];
  const float* Wf  = (const float*)d_in[13];
  const float* bf  = (const float*)d_in[14];
  float* out = (float*)d_out;

  char* wsb = (char*)d_ws;
  float*  h    = (float*)wsb;  wsb += (size_t)BATCH*DM*4;          // 4 MB
  ushort* xn   = (ushort*)wsb; wsb += (size_t)BATCH*DM*2;          // 2 MB
  ushort* xi   = (ushort*)wsb; wsb += (size_t)BATCH*DI*2;          // 8 MB
  ushort* sz   = (ushort*)wsb; wsb += (size_t)BATCH*DI*2;          // 8 MB
  ushort* WinT = (ushort*)wsb; wsb += (size_t)NL*2*DI*DM*2;        // 4 MB
  ushort* WoutT= (ushort*)wsb; wsb += (size_t)NL*DM*DI*2;          // 2 MB
  ushort* WxT  = (ushort*)wsb; wsb += (size_t)NL*80*DI*2;          // 0.64 MB

  k_prep<<<4352, 256, 0, stream>>>(Win, Wout, Wx, WinT, WoutT, WxT);
  k_proj_in<<<BATCH/16, 256, 0, stream>>>(x, Wp, bp, nw, h, xn);
  for (int l=0;l<NL;l++){
    k_blk0<<<dim3(BATCH/64, (2*DI)/64), 256, 0, stream>>>(
        xn, WinT + (size_t)l*2*DI*DM,
        cw + (size_t)l*DI*16, cb + (size_t)l*DI, xi, sz);
    k_ssm<<<BATCH/16, 512, 0, stream>>>(xi, sz, WxT + (size_t)l*80*DI,
        Wdt + (size_t)l*16*DI, bdt + (size_t)l*DI, Dd + (size_t)l*DI, xi);
    k_blk1<<<dim3(BATCH/32, DM/64), 256, 0, stream>>>(
        xi, WoutT + (size_t)l*DM*DI, h);
    if (l < NL-1)
      k_norm<0><<<BATCH/16, 256, 0, stream>>>(h, nw + (l+1)*DM, nullptr, nullptr, xn, nullptr);
    else
      k_norm<1><<<BATCH/16, 256, 0, stream>>>(h, nullptr, Wf, bf, nullptr, out);
  }
}